// Round 1
// 698.401 us; speedup vs baseline: 1.0437x; 1.0437x over previous
//
#include <hip/hip_runtime.h>

#define HH 384
#define WW 384
#define HWSZ (HH*WW)        // 147456
#define CIN 128
#define CQ 32
#define NB 4
#define NPIX (NB*HWSZ)      // 589824

__device__ __forceinline__ float sigmoidf_(float v){ return 1.0f/(1.0f + __expf(-v)); }

// ---------------- Kernel 0: prep — transpose weights, fold BN, softmax ----------------
// wt[c*32+o] = in_w[o*128+c]   (conv1 weights, [c][o] so the o-run is contiguous -> s_load_dwordx16)
// bt[c*32+o] = base_w[o*32+c]
// prm: [0..31] bn_scale, [32..63] bn_shift, [64..95] out_w, [96..99] softmax probs, [100] out_b
__global__ __launch_bounds__(256) void k_prep(
    const float* __restrict__ in_w, const float* __restrict__ base_w,
    const float* __restrict__ bn_g, const float* __restrict__ bn_b,
    const float* __restrict__ bn_m, const float* __restrict__ bn_v,
    const float* __restrict__ out_w, const float* __restrict__ out_b,
    const float* __restrict__ scales,
    float* __restrict__ wt, float* __restrict__ bt, float* __restrict__ prm){
  int t = threadIdx.x;
  for (int i = t; i < CIN*CQ; i += 256){ int c = i >> 5, o = i & 31; wt[i] = in_w[o*CIN + c]; }
  for (int i = t; i < CQ*CQ;  i += 256){ int c = i >> 5, o = i & 31; bt[i] = base_w[o*CQ + c]; }
  if (t < CQ){
    float inv = rsqrtf(bn_v[t] + 1e-3f);
    float g = bn_g[t]*inv;
    prm[t]      = g;
    prm[32 + t] = bn_b[t] - bn_m[t]*g;
    prm[64 + t] = out_w[t];
  }
  if (t == 0){
    float s0=scales[0], s1=scales[1], s2=scales[2], s3=scales[3];
    float mx = fmaxf(fmaxf(s0,s1), fmaxf(s2,s3));
    float e0=expf(s0-mx), e1=expf(s1-mx), e2=expf(s2-mx), e3=expf(s3-mx);
    float inv = 1.0f/(e0+e1+e2+e3);
    prm[96]=e0*inv; prm[97]=e1*inv; prm[98]=e2*inv; prm[99]=e3*inv;
    prm[100]=out_b[0];
  }
}

// ---------------- Kernel 1: conv1x1 128 -> 32, weights via SGPR scalar loads ----------------
__global__ __launch_bounds__(256) void k_conv1(const float* __restrict__ cen,
    const float* __restrict__ wt, const float* __restrict__ bvec,
    float* __restrict__ x) {
  int t = threadIdx.x;
  int p0  = blockIdx.x * 512 + t*2;     // block covers 512 aligned pixels (512 | HWSZ)
  int b   = p0 / HWSZ;                  // uniform per block
  int pix = p0 - b*HWSZ;
  const float* cb = cen + (size_t)b*CIN*HWSZ + pix;
  float2 acc[CQ];
  #pragma unroll
  for (int o=0;o<CQ;o++){ acc[o].x=0.f; acc[o].y=0.f; }
  #pragma unroll 2
  for (int c=0;c<CIN;c++){
    float2 v = *(const float2*)(cb + (size_t)c*HWSZ);
    const float* wc = wt + c*CQ;        // wave-uniform address -> s_load, FMA takes SGPR src
    #pragma unroll
    for (int o=0;o<CQ;o++){
      float w = wc[o];
      acc[o].x = fmaf(v.x, w, acc[o].x);
      acc[o].y = fmaf(v.y, w, acc[o].y);
    }
  }
  float* xb = x + (size_t)b*CQ*HWSZ + pix;
  #pragma unroll
  for (int o=0;o<CQ;o++){
    float bb = bvec[o];
    float2 r; r.x = acc[o].x + bb; r.y = acc[o].y + bb;
    *(float2*)(xb + (size_t)o*HWSZ) = r;
  }
}

// ------------- Kernel 2: LDS-tiled stencil + 1x1 convs -> attention scalar -------------
// Tile 8x64 interior, 2 pixels/thread (rows rr and rr+4). Halo overlap 1.91x (was 2.73x).
#define TH 8
#define TW 64
#define LDSW 72
#define LDSN (14*LDSW)   // 14 rows * 72 = 1008
#define GBX 6            // W/TW
#define GBY 48           // H/TH

__device__ __forceinline__ float stencil_eval(const float* p){
  float xv = p[0];
  float q0 = (xv-p[-LDSW-1])*(xv-p[ LDSW+1]);
  float q1 = (xv-p[-LDSW  ])*(xv-p[ LDSW  ]);
  float q2 = (xv-p[-LDSW+1])*(xv-p[ LDSW-1]);
  float q3 = (xv-p[-1     ])*(xv-p[ 1     ]);
  float os0 = fminf(fminf(q0,q1),fminf(q2,q3));
  float r0 = (xv-p[-3*LDSW-3])*(xv-p[ 3*LDSW+3]);
  float r1 = (xv-p[-3*LDSW  ])*(xv-p[ 3*LDSW  ]);
  float r2 = (xv-p[-3*LDSW+3])*(xv-p[ 3*LDSW-3]);
  float r3 = (xv-p[-3      ])*(xv-p[ 3       ]);
  float os1 = fminf(fminf(r0,r1),fminf(r2,r3));
  float v = fmaxf(os0,os1) + 0.5f*(os0+os1);
  return fmaxf(v, 0.0f);
}

__global__ __launch_bounds__(256) void k_att(const float* __restrict__ x,
    const float* __restrict__ mas, const float* __restrict__ bt,
    const float* __restrict__ prm, float* __restrict__ a_out) {
  __shared__ float tile[2][LDSN];
  int t = threadIdx.x;

  int gid = blockIdx.x;
  int b   = gid / (GBX*GBY);
  int rem = gid - b*(GBX*GBY);
  int ty  = rem / GBX;
  int tx  = rem - ty*GBX;
  int h0  = ty*TH, w0 = tx*TW;

  // staging coords (fixed across channels): 1008 cells, 4 rounds of 256
  int soff[4]; float sval[4];
  #pragma unroll
  for (int j=0;j<4;j++){
    int i = t + j*256;
    int r = i / LDSW, cc = i - r*LDSW;
    int hh = h0 - 3 + r, wq = w0 - 3 + cc;
    bool ok = (i < LDSN) && (cc < 70) &&
              ((unsigned)hh < (unsigned)HH) && ((unsigned)wq < (unsigned)WW);
    soff[j] = ok ? (hh*WW + wq) : 0;
    sval[j] = ok ? 1.0f : 0.0f;
  }

  int rr  = t >> 6, cc2 = t & 63;           // rows rr and rr+4 of the tile
  const int cbase0 = (3+rr)*LDSW + 3 + cc2;
  const int cbase1 = cbase0 + 4*LDSW;
  const float* xb = x + (size_t)b*CQ*HWSZ;

  float y0[CQ], y1[CQ];
  #pragma unroll
  for (int o=0;o<CQ;o++){ y0[o]=0.f; y1[o]=0.f; }

  #pragma unroll 2
  for (int c=0;c<CQ;c++){
    float* buf = tile[c&1];
    const float* xc = xb + (size_t)c*HWSZ;
    #pragma unroll
    for (int j=0;j<4;j++){
      int i = t + j*256;
      if (i < LDSN) buf[i] = sval[j] * xc[soff[j]];
    }
    __syncthreads();
    float fc0 = stencil_eval(buf + cbase0);
    float fc1 = stencil_eval(buf + cbase1);
    const float* wc = bt + c*CQ;            // wave-uniform -> s_load (SGPR weights)
    #pragma unroll
    for (int o=0;o<CQ;o++){
      float w = wc[o];
      y0[o] = fmaf(fc0, w, y0[o]);
      y1[o] = fmaf(fc1, w, y1[o]);
    }
    // next iteration writes the other buffer; its barrier orders reuse of this one
  }

  float w0p=prm[96], w1p=prm[97], w2p=prm[98], w3p=prm[99], ob=prm[100];
  float lin0=ob, lin1=ob;
  #pragma unroll
  for (int o=0;o<CQ;o++){
    float g=prm[o], sh=prm[32+o], ow=prm[64+o];
    float yy0 = fmaf(y0[o], g, sh);
    float yy1 = fmaf(y1[o], g, sh);
    lin0 = fmaf(ow*yy0, sigmoidf_(yy0), lin0);   // SiLU then 1x1 -> scalar
    lin1 = fmaf(ow*yy1, sigmoidf_(yy1), lin1);
  }
  float att0 = sigmoidf_(lin0);
  float att1 = sigmoidf_(lin1);

  int pa = b*HWSZ + (h0+rr)*WW + (w0+cc2);
  int pc = pa + 4*WW;
  float m0 = sigmoidf_(mas[pa]);
  float m1 = sigmoidf_(mas[pc]);
  a_out[pa] = (att0*m0)*w0p + m0*w1p + att0*w2p + w3p;
  a_out[pc] = (att1*m1)*w0p + m1*w1p + att1*w2p + w3p;
}

// ---------------- Kernel 3: out = cen * a (broadcast over 128 ch) ----------------
__global__ __launch_bounds__(256) void k_out(const float* __restrict__ cen,
    const float* __restrict__ a, float* __restrict__ out){
  unsigned i = blockIdx.x*256u + threadIdx.x;   // float4 index
  unsigned e = i*4u;
  unsigned bc  = e / HWSZ;                      // b*128 + c
  unsigned pix = e - bc*HWSZ;
  unsigned b   = bc >> 7;
  float4 v  = ((const float4*)cen)[i];
  float4 av = ((const float4*)a)[(b*HWSZ + pix) >> 2];
  float4 r;
  r.x = v.x*av.x; r.y = v.y*av.y; r.z = v.z*av.z; r.w = v.w*av.w;
  ((float4*)out)[i] = r;
}

extern "C" void kernel_launch(void* const* d_in, const int* in_sizes, int n_in,
                              void* d_out, int out_size, void* d_ws, size_t ws_size,
                              hipStream_t stream) {
  const float* cen    = (const float*)d_in[0];
  const float* mas    = (const float*)d_in[1];
  const float* scales = (const float*)d_in[2];
  const float* in_w   = (const float*)d_in[3];
  const float* in_b   = (const float*)d_in[4];
  const float* base_w = (const float*)d_in[5];
  const float* bn_g   = (const float*)d_in[6];
  const float* bn_b   = (const float*)d_in[7];
  const float* bn_m   = (const float*)d_in[8];
  const float* bn_v   = (const float*)d_in[9];
  const float* out_w  = (const float*)d_in[10];
  const float* out_b  = (const float*)d_in[11];
  float* out = (float*)d_out;

  float* x   = (float*)d_ws;                    // B*CQ*HW floats = 75.5 MB
  float* a   = x  + (size_t)NB*CQ*HWSZ;         // B*HW floats = 2.36 MB
  float* wt  = a  + (size_t)NB*HWSZ;            // 4096 floats
  float* bt  = wt + (size_t)CIN*CQ;             // 1024 floats
  float* prm = bt + (size_t)CQ*CQ;              // 128 floats

  k_prep <<<1, 256, 0, stream>>>(in_w, base_w, bn_g, bn_b, bn_m, bn_v,
                                 out_w, out_b, scales, wt, bt, prm);
  k_conv1<<<NPIX/512, 256, 0, stream>>>(cen, wt, in_b, x);
  k_att  <<<NB*GBX*GBY, 256, 0, stream>>>(x, mas, bt, prm, a);
  k_out  <<<(NB*CIN*HWSZ)/1024, 256, 0, stream>>>(cen, a, out);
}

// Round 2
// 633.861 us; speedup vs baseline: 1.1499x; 1.1018x over previous
//
#include <hip/hip_runtime.h>

#define HH 384
#define WW 384
#define HWSZ (HH*WW)        // 147456
#define CIN 128
#define CQ 32
#define NB 4
#define NPIX (NB*HWSZ)      // 589824

__device__ __forceinline__ float sigmoidf_(float v){ return 1.0f/(1.0f + __expf(-v)); }

// ---------------- Kernel 0: prep — transpose weights, fold BN, softmax ----------------
// wt[c*32+o] = in_w[o*128+c]; bt[c*32+o] = base_w[o*32+c]
// prm: [0..31] bn_scale, [32..63] bn_shift, [64..95] out_w, [96..99] softmax probs, [100] out_b
__global__ __launch_bounds__(256) void k_prep(
    const float* __restrict__ in_w, const float* __restrict__ base_w,
    const float* __restrict__ bn_g, const float* __restrict__ bn_b,
    const float* __restrict__ bn_m, const float* __restrict__ bn_v,
    const float* __restrict__ out_w, const float* __restrict__ out_b,
    const float* __restrict__ scales,
    float* __restrict__ wt, float* __restrict__ bt, float* __restrict__ prm){
  int t = threadIdx.x;
  for (int i = t; i < CIN*CQ; i += 256){ int c = i >> 5, o = i & 31; wt[i] = in_w[o*CIN + c]; }
  for (int i = t; i < CQ*CQ;  i += 256){ int c = i >> 5, o = i & 31; bt[i] = base_w[o*CQ + c]; }
  if (t < CQ){
    float inv = rsqrtf(bn_v[t] + 1e-3f);
    float g = bn_g[t]*inv;
    prm[t]      = g;
    prm[32 + t] = bn_b[t] - bn_m[t]*g;
    prm[64 + t] = out_w[t];
  }
  if (t == 0){
    float s0=scales[0], s1=scales[1], s2=scales[2], s3=scales[3];
    float mx = fmaxf(fmaxf(s0,s1), fmaxf(s2,s3));
    float e0=expf(s0-mx), e1=expf(s1-mx), e2=expf(s2-mx), e3=expf(s3-mx);
    float inv = 1.0f/(e0+e1+e2+e3);
    prm[96]=e0*inv; prm[97]=e1*inv; prm[98]=e2*inv; prm[99]=e3*inv;
    prm[100]=out_b[0];
  }
}

// ---------------- Kernel 1: conv1x1 128 -> 32 ----------------
// SGPR weights (wave-uniform wt reads) + 4-channel load batches with explicit
// next-batch prefetch: 4-8 global loads in flight per wave while 256 FMAs retire.
__global__ __launch_bounds__(256) void k_conv1(const float* __restrict__ cen,
    const float* __restrict__ wt, const float* __restrict__ bvec,
    float* __restrict__ x) {
  int t = threadIdx.x;
  int p0  = blockIdx.x * 512 + t*2;     // 512 aligned pixels per block (512 | HWSZ)
  int b   = p0 / HWSZ;                  // uniform per block
  int pix = p0 - b*HWSZ;
  const float* cb = cen + (size_t)b*CIN*HWSZ + pix;
  float2 acc[CQ];
  #pragma unroll
  for (int o=0;o<CQ;o++){ float bb = bvec[o]; acc[o].x=bb; acc[o].y=bb; }

  float2 cur[4], nxt[4];
  #pragma unroll
  for (int k=0;k<4;k++) cur[k] = *(const float2*)(cb + (size_t)k*HWSZ);

  for (int c=0;c<CIN;c+=4){
    if (c+4 < CIN){
      #pragma unroll
      for (int k=0;k<4;k++) nxt[k] = *(const float2*)(cb + (size_t)(c+4+k)*HWSZ);
    }
    const float* wc = wt + c*CQ;        // wave-uniform -> s_load, FMA takes SGPR src
    #pragma unroll
    for (int k=0;k<4;k++){
      #pragma unroll
      for (int o=0;o<CQ;o++){
        float w = wc[k*CQ+o];
        acc[o].x = fmaf(cur[k].x, w, acc[o].x);
        acc[o].y = fmaf(cur[k].y, w, acc[o].y);
      }
    }
    #pragma unroll
    for (int k=0;k<4;k++) cur[k] = nxt[k];
  }
  float* xb = x + (size_t)b*CQ*HWSZ + pix;
  #pragma unroll
  for (int o=0;o<CQ;o++) *(float2*)(xb + (size_t)o*HWSZ) = acc[o];
}

// ------------- Kernel 2: LDS-tiled stencil + 1x1 convs -> attention scalar -------------
// 8x64 interior tile; each thread owns a HORIZONTAL pixel pair (cols 2ct, 2ct+1):
// stencil loads become aligned ds_read_b64s shared between the pair (12-14 LDS instrs
// per 2 px vs ~22). Staging is register-prefetched (T14): next channel's global loads
// issue before the current stencil, ds_write after the barrier.
#define TH 8
#define TW 64
#define LDSW 72
#define LDSN (14*LDSW)   // 1008
#define GBX 6            // W/TW
#define GBY 48           // H/TH

__global__ __launch_bounds__(256) void k_att(const float* __restrict__ x,
    const float* __restrict__ mas, const float* __restrict__ bt,
    const float* __restrict__ prm, float* __restrict__ a_out) {
  __shared__ float tile[2][LDSN];
  int t = threadIdx.x;

  int gid = blockIdx.x;
  int b   = gid / (GBX*GBY);
  int rem = gid - b*(GBX*GBY);
  int ty  = rem / GBX;
  int tx  = rem - ty*GBX;
  int h0  = ty*TH, w0 = tx*TW;

  // staging coords (fixed across channels): 1008 cells, 4 rounds of 256
  int soff[4]; float sval[4];
  #pragma unroll
  for (int j=0;j<4;j++){
    int i = t + j*256;
    int r = i / LDSW, cc = i - r*LDSW;
    int hh = h0 - 3 + r, wq = w0 - 3 + cc;
    bool ok = (i < LDSN) && (cc < 70) &&
              ((unsigned)hh < (unsigned)HH) && ((unsigned)wq < (unsigned)WW);
    soff[j] = ok ? (hh*WW + wq) : 0;
    sval[j] = ok ? 1.0f : 0.0f;
  }

  int rr = t >> 5;                  // row 0..7
  int ct = t & 31;                  // col pair 0..31
  const int R = 3 + rr, C = 3 + 2*ct;   // C odd -> all f2 offsets below even (8B aligned)
  const int o_m3 = (R-3)*LDSW + C, o_m1 = (R-1)*LDSW + C,
            o_0  =  R   *LDSW + C, o_p1 = (R+1)*LDSW + C,
            o_p3 = (R+3)*LDSW + C;
  const float* xb = x + (size_t)b*CQ*HWSZ;

  float y0[CQ], y1[CQ];
  #pragma unroll
  for (int o=0;o<CQ;o++){ y0[o]=0.f; y1[o]=0.f; }

  float rg[4];
  #pragma unroll
  for (int j=0;j<4;j++) rg[j] = xb[soff[j]];   // channel 0 prefetch

  #pragma unroll 2
  for (int c=0;c<CQ;c++){
    float* buf = tile[c&1];
    #pragma unroll
    for (int j=0;j<4;j++){
      int i = t + j*256;
      if (i < LDSN) buf[i] = sval[j]*rg[j];
    }
    float rg2[4];
    if (c+1 < CQ){
      const float* xn = xb + (size_t)(c+1)*HWSZ;
      #pragma unroll
      for (int j=0;j<4;j++) rg2[j] = xn[soff[j]];  // in flight across barrier+stencil
    }
    __syncthreads();
    const float* p = buf;
    float2 m3a = *(const float2*)(p + o_m3 - 3);
    float  m3b0 = p[o_m3], m3b1 = p[o_m3 + 1];
    float2 m3c = *(const float2*)(p + o_m3 + 3);
    float2 m1a = *(const float2*)(p + o_m1 - 1);
    float2 m1b = *(const float2*)(p + o_m1 + 1);
    float2 z0  = *(const float2*)(p + o_0  - 3);
    float2 z1  = *(const float2*)(p + o_0  - 1);
    float2 z2  = *(const float2*)(p + o_0  + 1);
    float2 z3  = *(const float2*)(p + o_0  + 3);
    float2 p1a = *(const float2*)(p + o_p1 - 1);
    float2 p1b = *(const float2*)(p + o_p1 + 1);
    float2 p3a = *(const float2*)(p + o_p3 - 3);
    float  p3b0 = p[o_p3], p3b1 = p[o_p3 + 1];
    float2 p3c = *(const float2*)(p + o_p3 + 3);

    // px0: center (R,C) = z1.y
    float xv = z1.y;
    float q0 = (xv-m1a.x)*(xv-p1b.x);
    float q1 = (xv-m1a.y)*(xv-p1a.y);
    float q2 = (xv-m1b.x)*(xv-p1a.x);
    float q3 = (xv-z1.x )*(xv-z2.x );
    float os0 = fminf(fminf(q0,q1),fminf(q2,q3));
    float r0 = (xv-m3a.x)*(xv-p3c.x);
    float r1 = (xv-m3b0 )*(xv-p3b0 );
    float r2 = (xv-m3c.x)*(xv-p3a.x);
    float r3 = (xv-z0.x )*(xv-z3.x );
    float os1 = fminf(fminf(r0,r1),fminf(r2,r3));
    float v0 = fmaxf(os0,os1) + 0.5f*(os0+os1);
    float fc0 = fmaxf(v0, 0.0f);

    // px1: center (R,C+1) = z2.x
    float xw = z2.x;
    float u0 = (xw-m1a.y)*(xw-p1b.y);
    float u1 = (xw-m1b.x)*(xw-p1b.x);
    float u2 = (xw-m1b.y)*(xw-p1a.y);
    float u3 = (xw-z1.y )*(xw-z2.y );
    float ps0 = fminf(fminf(u0,u1),fminf(u2,u3));
    float s0 = (xw-m3a.y)*(xw-p3c.y);
    float s1 = (xw-m3b1 )*(xw-p3b1 );
    float s2 = (xw-m3c.y)*(xw-p3a.y);
    float s3 = (xw-z0.y )*(xw-z3.y );
    float ps1 = fminf(fminf(s0,s1),fminf(s2,s3));
    float v1 = fmaxf(ps0,ps1) + 0.5f*(ps0+ps1);
    float fc1 = fmaxf(v1, 0.0f);

    const float* wc = bt + c*CQ;            // wave-uniform -> SGPR weights
    #pragma unroll
    for (int o=0;o<CQ;o++){
      float w = wc[o];
      y0[o] = fmaf(fc0, w, y0[o]);
      y1[o] = fmaf(fc1, w, y1[o]);
    }
    #pragma unroll
    for (int j=0;j<4;j++) rg[j] = rg2[j];
    // next iteration writes the other buffer; its barrier orders reuse of this one
  }

  float w0p=prm[96], w1p=prm[97], w2p=prm[98], w3p=prm[99], ob=prm[100];
  float lin0=ob, lin1=ob;
  #pragma unroll
  for (int o=0;o<CQ;o++){
    float g=prm[o], sh=prm[32+o], ow=prm[64+o];
    float yy0 = fmaf(y0[o], g, sh);
    float yy1 = fmaf(y1[o], g, sh);
    lin0 = fmaf(ow*yy0, sigmoidf_(yy0), lin0);   // SiLU then 1x1 -> scalar
    lin1 = fmaf(ow*yy1, sigmoidf_(yy1), lin1);
  }
  float att0 = sigmoidf_(lin0);
  float att1 = sigmoidf_(lin1);

  int pa = b*HWSZ + (h0+rr)*WW + (w0 + 2*ct);   // even dword offset -> 8B aligned
  float2 mm = *(const float2*)(mas + pa);
  float m0 = sigmoidf_(mm.x);
  float m1 = sigmoidf_(mm.y);
  float2 res;
  res.x = (att0*m0)*w0p + m0*w1p + att0*w2p + w3p;
  res.y = (att1*m1)*w0p + m1*w1p + att1*w2p + w3p;
  *(float2*)(a_out + pa) = res;
}

// ---------------- Kernel 3: out = cen * a (broadcast over 128 ch) ----------------
__global__ __launch_bounds__(256) void k_out(const float* __restrict__ cen,
    const float* __restrict__ a, float* __restrict__ out){
  unsigned i = blockIdx.x*256u + threadIdx.x;   // float4 index
  unsigned e = i*4u;
  unsigned bc  = e / HWSZ;                      // b*128 + c
  unsigned pix = e - bc*HWSZ;
  unsigned b   = bc >> 7;
  float4 v  = ((const float4*)cen)[i];
  float4 av = ((const float4*)a)[(b*HWSZ + pix) >> 2];
  float4 r;
  r.x = v.x*av.x; r.y = v.y*av.y; r.z = v.z*av.z; r.w = v.w*av.w;
  ((float4*)out)[i] = r;
}

extern "C" void kernel_launch(void* const* d_in, const int* in_sizes, int n_in,
                              void* d_out, int out_size, void* d_ws, size_t ws_size,
                              hipStream_t stream) {
  const float* cen    = (const float*)d_in[0];
  const float* mas    = (const float*)d_in[1];
  const float* scales = (const float*)d_in[2];
  const float* in_w   = (const float*)d_in[3];
  const float* in_b   = (const float*)d_in[4];
  const float* base_w = (const float*)d_in[5];
  const float* bn_g   = (const float*)d_in[6];
  const float* bn_b   = (const float*)d_in[7];
  const float* bn_m   = (const float*)d_in[8];
  const float* bn_v   = (const float*)d_in[9];
  const float* out_w  = (const float*)d_in[10];
  const float* out_b  = (const float*)d_in[11];
  float* out = (float*)d_out;

  float* x   = (float*)d_ws;                    // B*CQ*HW floats = 75.5 MB
  float* a   = x  + (size_t)NB*CQ*HWSZ;         // B*HW floats = 2.36 MB
  float* wt  = a  + (size_t)NB*HWSZ;            // 4096 floats
  float* bt  = wt + (size_t)CIN*CQ;             // 1024 floats
  float* prm = bt + (size_t)CQ*CQ;              // 128 floats

  k_prep <<<1, 256, 0, stream>>>(in_w, base_w, bn_g, bn_b, bn_m, bn_v,
                                 out_w, out_b, scales, wt, bt, prm);
  k_conv1<<<NPIX/512, 256, 0, stream>>>(cen, wt, in_b, x);
  k_att  <<<NB*GBX*GBY, 256, 0, stream>>>(x, mas, bt, prm, a);
  k_out  <<<(NB*CIN*HWSZ)/1024, 256, 0, stream>>>(cen, a, out);
}

// Round 3
// 605.944 us; speedup vs baseline: 1.2029x; 1.0461x over previous
//
#include <hip/hip_runtime.h>

#define HH 384
#define WW 384
#define HWSZ (HH*WW)        // 147456
#define CIN 128
#define CQ 32
#define NB 4
#define NPIX (NB*HWSZ)      // 589824

typedef float __attribute__((ext_vector_type(2))) f2v;

__device__ __forceinline__ float sigmoidf_(float v){ return 1.0f/(1.0f + __expf(-v)); }

// ---------------- Kernel 0: prep — transpose weights, fold BN, softmax ----------------
// wt[c*32+o] = in_w[o*128+c]; bt[c*32+o] = base_w[o*32+c]
// prm: [0..31] bn_scale, [32..63] bn_shift, [64..95] out_w, [96..99] softmax probs, [100] out_b
__global__ __launch_bounds__(256) void k_prep(
    const float* __restrict__ in_w, const float* __restrict__ base_w,
    const float* __restrict__ bn_g, const float* __restrict__ bn_b,
    const float* __restrict__ bn_m, const float* __restrict__ bn_v,
    const float* __restrict__ out_w, const float* __restrict__ out_b,
    const float* __restrict__ scales,
    float* __restrict__ wt, float* __restrict__ bt, float* __restrict__ prm){
  int t = threadIdx.x;
  for (int i = t; i < CIN*CQ; i += 256){ int c = i >> 5, o = i & 31; wt[i] = in_w[o*CIN + c]; }
  for (int i = t; i < CQ*CQ;  i += 256){ int c = i >> 5, o = i & 31; bt[i] = base_w[o*CQ + c]; }
  if (t < CQ){
    float inv = rsqrtf(bn_v[t] + 1e-3f);
    float g = bn_g[t]*inv;
    prm[t]      = g;
    prm[32 + t] = bn_b[t] - bn_m[t]*g;
    prm[64 + t] = out_w[t];
  }
  if (t == 0){
    float s0=scales[0], s1=scales[1], s2=scales[2], s3=scales[3];
    float mx = fmaxf(fmaxf(s0,s1), fmaxf(s2,s3));
    float e0=expf(s0-mx), e1=expf(s1-mx), e2=expf(s2-mx), e3=expf(s3-mx);
    float inv = 1.0f/(e0+e1+e2+e3);
    prm[96]=e0*inv; prm[97]=e1*inv; prm[98]=e2*inv; prm[99]=e3*inv;
    prm[100]=out_b[0];
  }
}

// ---------------- Kernel 1: conv1x1 128 -> 32 ----------------
// SGPR weights + 4-channel load batches with explicit next-batch prefetch.
// cen loads are non-temporal (single use) so x stays L3-resident for k_att.
__global__ __launch_bounds__(256) void k_conv1(const float* __restrict__ cen,
    const float* __restrict__ wt, const float* __restrict__ bvec,
    float* __restrict__ x) {
  int t = threadIdx.x;
  int p0  = blockIdx.x * 512 + t*2;     // 512 aligned pixels per block (512 | HWSZ)
  int b   = p0 / HWSZ;                  // uniform per block
  int pix = p0 - b*HWSZ;
  const float* cb = cen + (size_t)b*CIN*HWSZ + pix;
  float2 acc[CQ];
  #pragma unroll
  for (int o=0;o<CQ;o++){ float bb = bvec[o]; acc[o].x=bb; acc[o].y=bb; }

  f2v cur[4], nxt[4];
  #pragma unroll
  for (int k=0;k<4;k++) cur[k] = __builtin_nontemporal_load((const f2v*)(cb + (size_t)k*HWSZ));

  for (int c=0;c<CIN;c+=4){
    if (c+4 < CIN){
      #pragma unroll
      for (int k=0;k<4;k++) nxt[k] = __builtin_nontemporal_load((const f2v*)(cb + (size_t)(c+4+k)*HWSZ));
    }
    const float* wc = wt + c*CQ;        // wave-uniform -> s_load, FMA takes SGPR src
    #pragma unroll
    for (int k=0;k<4;k++){
      #pragma unroll
      for (int o=0;o<CQ;o++){
        float w = wc[k*CQ+o];
        acc[o].x = fmaf(cur[k].x, w, acc[o].x);
        acc[o].y = fmaf(cur[k].y, w, acc[o].y);
      }
    }
    #pragma unroll
    for (int k=0;k<4;k++) cur[k] = nxt[k];
  }
  float* xb = x + (size_t)b*CQ*HWSZ + pix;
  #pragma unroll
  for (int o=0;o<CQ;o++) *(float2*)(xb + (size_t)o*HWSZ) = acc[o];
}

// ------- Kernel 2: LDS-tiled stencil + 1x1 convs -> attention -> FUSED out = cen*a -------
// 8x64 interior tile, horizontal pixel pair per thread (aligned ds_read_b64 stencil),
// register-prefetched staging (T14). After the per-tile attention scalar is known,
// the block streams its 128 cen channels (nt loads) and writes out (nt stores) directly:
// kills the `a` round-trip and the separate k_out dispatch.
#define TH 8
#define TW 64
#define LDSW 72
#define LDSN (14*LDSW)   // 1008
#define GBX 6            // W/TW
#define GBY 48           // H/TH

__global__ __launch_bounds__(256) void k_att(const float* __restrict__ x,
    const float* __restrict__ cen, const float* __restrict__ mas,
    const float* __restrict__ bt, const float* __restrict__ prm,
    float* __restrict__ out) {
  __shared__ float tile[2][LDSN];
  int t = threadIdx.x;

  int gid = blockIdx.x;
  int b   = gid / (GBX*GBY);
  int rem = gid - b*(GBX*GBY);
  int ty  = rem / GBX;
  int tx  = rem - ty*GBX;
  int h0  = ty*TH, w0 = tx*TW;

  // staging coords (fixed across channels): 1008 cells, 4 rounds of 256
  int soff[4]; float sval[4];
  #pragma unroll
  for (int j=0;j<4;j++){
    int i = t + j*256;
    int r = i / LDSW, cc = i - r*LDSW;
    int hh = h0 - 3 + r, wq = w0 - 3 + cc;
    bool ok = (i < LDSN) && (cc < 70) &&
              ((unsigned)hh < (unsigned)HH) && ((unsigned)wq < (unsigned)WW);
    soff[j] = ok ? (hh*WW + wq) : 0;
    sval[j] = ok ? 1.0f : 0.0f;
  }

  int rr = t >> 5;                  // row 0..7
  int ct = t & 31;                  // col pair 0..31
  const int R = 3 + rr, C = 3 + 2*ct;   // C odd -> all f2 offsets below even (8B aligned)
  const int o_m3 = (R-3)*LDSW + C, o_m1 = (R-1)*LDSW + C,
            o_0  =  R   *LDSW + C, o_p1 = (R+1)*LDSW + C,
            o_p3 = (R+3)*LDSW + C;
  const float* xb = x + (size_t)b*CQ*HWSZ;

  float y0[CQ], y1[CQ];
  #pragma unroll
  for (int o=0;o<CQ;o++){ y0[o]=0.f; y1[o]=0.f; }

  float rg[4];
  #pragma unroll
  for (int j=0;j<4;j++) rg[j] = xb[soff[j]];   // channel 0 prefetch

  #pragma unroll 2
  for (int c=0;c<CQ;c++){
    float* buf = tile[c&1];
    #pragma unroll
    for (int j=0;j<4;j++){
      int i = t + j*256;
      if (i < LDSN) buf[i] = sval[j]*rg[j];
    }
    float rg2[4];
    if (c+1 < CQ){
      const float* xn = xb + (size_t)(c+1)*HWSZ;
      #pragma unroll
      for (int j=0;j<4;j++) rg2[j] = xn[soff[j]];  // in flight across barrier+stencil
    }
    __syncthreads();
    const float* p = buf;
    float2 m3a = *(const float2*)(p + o_m3 - 3);
    float  m3b0 = p[o_m3], m3b1 = p[o_m3 + 1];
    float2 m3c = *(const float2*)(p + o_m3 + 3);
    float2 m1a = *(const float2*)(p + o_m1 - 1);
    float2 m1b = *(const float2*)(p + o_m1 + 1);
    float2 z0  = *(const float2*)(p + o_0  - 3);
    float2 z1  = *(const float2*)(p + o_0  - 1);
    float2 z2  = *(const float2*)(p + o_0  + 1);
    float2 z3  = *(const float2*)(p + o_0  + 3);
    float2 p1a = *(const float2*)(p + o_p1 - 1);
    float2 p1b = *(const float2*)(p + o_p1 + 1);
    float2 p3a = *(const float2*)(p + o_p3 - 3);
    float  p3b0 = p[o_p3], p3b1 = p[o_p3 + 1];
    float2 p3c = *(const float2*)(p + o_p3 + 3);

    // px0: center (R,C) = z1.y
    float xv = z1.y;
    float q0 = (xv-m1a.x)*(xv-p1b.x);
    float q1 = (xv-m1a.y)*(xv-p1a.y);
    float q2 = (xv-m1b.x)*(xv-p1a.x);
    float q3 = (xv-z1.x )*(xv-z2.x );
    float os0 = fminf(fminf(q0,q1),fminf(q2,q3));
    float r0 = (xv-m3a.x)*(xv-p3c.x);
    float r1 = (xv-m3b0 )*(xv-p3b0 );
    float r2 = (xv-m3c.x)*(xv-p3a.x);
    float r3 = (xv-z0.x )*(xv-z3.x );
    float os1 = fminf(fminf(r0,r1),fminf(r2,r3));
    float v0 = fmaxf(os0,os1) + 0.5f*(os0+os1);
    float fc0 = fmaxf(v0, 0.0f);

    // px1: center (R,C+1) = z2.x
    float xw = z2.x;
    float u0 = (xw-m1a.y)*(xw-p1b.y);
    float u1 = (xw-m1b.x)*(xw-p1b.x);
    float u2 = (xw-m1b.y)*(xw-p1a.y);
    float u3 = (xw-z1.y )*(xw-z2.y );
    float ps0 = fminf(fminf(u0,u1),fminf(u2,u3));
    float s0 = (xw-m3a.y)*(xw-p3c.y);
    float s1 = (xw-m3b1 )*(xw-p3b1 );
    float s2 = (xw-m3c.y)*(xw-p3a.y);
    float s3 = (xw-z0.y )*(xw-z3.y );
    float ps1 = fminf(fminf(s0,s1),fminf(s2,s3));
    float v1 = fmaxf(ps0,ps1) + 0.5f*(ps0+ps1);
    float fc1 = fmaxf(v1, 0.0f);

    const float* wc = bt + c*CQ;            // wave-uniform -> SGPR weights
    #pragma unroll
    for (int o=0;o<CQ;o++){
      float w = wc[o];
      y0[o] = fmaf(fc0, w, y0[o]);
      y1[o] = fmaf(fc1, w, y1[o]);
    }
    #pragma unroll
    for (int j=0;j<4;j++) rg[j] = rg2[j];
    // next iteration writes the other buffer; its barrier orders reuse of this one
  }

  float w0p=prm[96], w1p=prm[97], w2p=prm[98], w3p=prm[99], ob=prm[100];
  float lin0=ob, lin1=ob;
  #pragma unroll
  for (int o=0;o<CQ;o++){
    float g=prm[o], sh=prm[32+o], ow=prm[64+o];
    float yy0 = fmaf(y0[o], g, sh);
    float yy1 = fmaf(y1[o], g, sh);
    lin0 = fmaf(ow*yy0, sigmoidf_(yy0), lin0);   // SiLU then 1x1 -> scalar
    lin1 = fmaf(ow*yy1, sigmoidf_(yy1), lin1);
  }
  float att0 = sigmoidf_(lin0);
  float att1 = sigmoidf_(lin1);

  int pix = (h0+rr)*WW + (w0 + 2*ct);           // even dword offset -> 8B aligned
  float2 mm = *(const float2*)(mas + b*HWSZ + pix);
  float m0 = sigmoidf_(mm.x);
  float m1 = sigmoidf_(mm.y);
  float a0 = (att0*m0)*w0p + m0*w1p + att0*w2p + w3p;
  float a1 = (att1*m1)*w0p + m1*w1p + att1*w2p + w3p;

  // ---- fused out phase: out[b,c,pix..pix+1] = cen * a, streamed over 128 channels ----
  const float* cb = cen + (size_t)b*CIN*HWSZ + pix;
  float*       od = out + (size_t)b*CIN*HWSZ + pix;
  #pragma unroll 8
  for (int c=0;c<CIN;c++){
    f2v v = __builtin_nontemporal_load((const f2v*)(cb + (size_t)c*HWSZ));
    v.x *= a0; v.y *= a1;
    __builtin_nontemporal_store(v, (f2v*)(od + (size_t)c*HWSZ));
  }
}

extern "C" void kernel_launch(void* const* d_in, const int* in_sizes, int n_in,
                              void* d_out, int out_size, void* d_ws, size_t ws_size,
                              hipStream_t stream) {
  const float* cen    = (const float*)d_in[0];
  const float* mas    = (const float*)d_in[1];
  const float* scales = (const float*)d_in[2];
  const float* in_w   = (const float*)d_in[3];
  const float* in_b   = (const float*)d_in[4];
  const float* base_w = (const float*)d_in[5];
  const float* bn_g   = (const float*)d_in[6];
  const float* bn_b   = (const float*)d_in[7];
  const float* bn_m   = (const float*)d_in[8];
  const float* bn_v   = (const float*)d_in[9];
  const float* out_w  = (const float*)d_in[10];
  const float* out_b  = (const float*)d_in[11];
  float* out = (float*)d_out;

  float* x   = (float*)d_ws;                    // B*CQ*HW floats = 75.5 MB
  float* wt  = x  + (size_t)NB*CQ*HWSZ;         // 4096 floats
  float* bt  = wt + (size_t)CIN*CQ;             // 1024 floats
  float* prm = bt + (size_t)CQ*CQ;              // 128 floats

  k_prep <<<1, 256, 0, stream>>>(in_w, base_w, bn_g, bn_b, bn_m, bn_v,
                                 out_w, out_b, scales, wt, bt, prm);
  k_conv1<<<NPIX/512, 256, 0, stream>>>(cen, wt, in_b, x);
  k_att  <<<NB*GBX*GBY, 256, 0, stream>>>(x, cen, mas, bt, prm, out);
}